// Round 2
// baseline (976.772 us; speedup 1.0000x reference)
//
#include <hip/hip_runtime.h>
#include <hip/hip_bf16.h>

typedef __attribute__((ext_vector_type(8))) short short8;
typedef __attribute__((ext_vector_type(4))) float f32x4;

#define T_LEN   1024
#define KKEEP   922
#define DDIM    768
#define NBATCH  64

#define BM 128
#define BN 128
#define BK 32
#define LDSK 40   // padded LDS row stride in ushorts (80B, 16B-aligned)

// C_T (DCT-II, ortho) rows [0,922) of a 1024-point DCT, bf16, [1024][1024], pad rows zero.
__global__ void gen_C1(__hip_bfloat16* __restrict__ C1) {
    int idx = blockIdx.x * 256 + threadIdx.x;
    if (idx >= 1024 * 1024) return;
    int kk = idx >> 10;
    int t  = idx & 1023;
    float val = 0.0f;
    if (kk < KKEEP) {
        // replicate jax fp32 op order: (pi*(2t+1)) * k / (2N)
        float a1 = 3.14159265358979323846f * (2.0f * (float)t + 1.0f);
        float a2 = a1 * (float)kk;
        float a3 = a2 / 2048.0f;
        float s  = (kk == 0) ? sqrtf(1.0f / 1024.0f) : sqrtf(2.0f / 1024.0f);
        val = s * cosf(a3);
    }
    C1[idx] = __float2bfloat16(val);
}

// A2[n][m] = C_k[m][n] (DCT-III = transpose of ortho DCT-II, size 922), bf16,
// [1024][928], zero-padded beyond 922 in both dims.
__global__ void gen_C2T(__hip_bfloat16* __restrict__ A2) {
    int idx = blockIdx.x * 256 + threadIdx.x;
    if (idx >= 1024 * 928) return;
    int n = idx / 928;
    int m = idx - n * 928;
    float val = 0.0f;
    if (n < KKEEP && m < KKEEP) {
        float a1 = 3.14159265358979323846f * (2.0f * (float)n + 1.0f);
        float a2 = a1 * (float)m;
        float a3 = a2 / 1844.0f;
        float s  = (m == 0) ? sqrtf(1.0f / 922.0f) : sqrtf(2.0f / 922.0f);
        val = s * cosf(a3);
    }
    A2[idx] = __float2bfloat16(val);
}

// C[b] (MxN fp32, M=922 valid, N=768) = A (bf16 [*, lda], row-major, shared) x B[b] (fp32 [bRows,768])
// 128x128 tile, 4 waves, 16x16x32 bf16 MFMA, double-buffered LDS.
__global__ __launch_bounds__(256)
void gemm_dct(const __hip_bfloat16* __restrict__ A, int lda, int ksteps,
              const float* __restrict__ B, int bRows, long long bStride,
              float* __restrict__ C, long long cStride)
{
    __shared__ __hip_bfloat16 As[2][BM * LDSK];
    __shared__ __hip_bfloat16 Bs[2][BN * LDSK];

    const int tid   = threadIdx.x;
    const int mBase = blockIdx.y * BM;
    const int nBase = blockIdx.x * BN;

    const float* __restrict__ Bb = B + (long long)blockIdx.z * bStride;
    float* __restrict__       Cb = C + (long long)blockIdx.z * cStride;

    auto stageA = [&](int buf, int k0) {
        int r = tid >> 1, half = tid & 1;
        const uint4* src = (const uint4*)(A + (size_t)(mBase + r) * lda + k0 + half * 16);
        uint4 v0 = src[0], v1 = src[1];
        uint4* dst = (uint4*)&As[buf][r * LDSK + half * 16];
        dst[0] = v0; dst[1] = v1;
    };
    auto stageB = [&](int buf, int k0) {
        #pragma unroll
        for (int p = 0; p < 4; ++p) {
            int idx = p * 256 + tid;
            int k   = idx & 31;           // consecutive lanes -> consecutive k rows
            int n4  = (idx >> 5) * 4;
            int gk  = k0 + k;
            float4 v = make_float4(0.f, 0.f, 0.f, 0.f);
            if (gk < bRows) v = *(const float4*)(Bb + (size_t)gk * DDIM + nBase + n4);
            __hip_bfloat16* d = &Bs[buf][n4 * LDSK + k];   // transposed: Bs[n][k]
            d[0 * LDSK] = __float2bfloat16(v.x);
            d[1 * LDSK] = __float2bfloat16(v.y);
            d[2 * LDSK] = __float2bfloat16(v.z);
            d[3 * LDSK] = __float2bfloat16(v.w);
        }
    };

    const int lane = tid & 63;
    const int wid  = tid >> 6;
    const int wm   = (wid >> 1) * 64;
    const int wn   = (wid & 1) * 64;
    const int lr   = lane & 15;
    const int g8   = (lane >> 4) * 8;

    f32x4 acc[4][4] = {};

    stageA(0, 0);
    stageB(0, 0);
    __syncthreads();

    for (int s = 0; s < ksteps; ++s) {
        int buf = s & 1;
        if (s + 1 < ksteps) {
            stageA(buf ^ 1, (s + 1) * BK);
            stageB(buf ^ 1, (s + 1) * BK);
        }
        short8 af[4], bfr[4];
        #pragma unroll
        for (int m = 0; m < 4; ++m)
            af[m] = *(const short8*)&As[buf][(wm + m * 16 + lr) * LDSK + g8];
        #pragma unroll
        for (int n = 0; n < 4; ++n)
            bfr[n] = *(const short8*)&Bs[buf][(wn + n * 16 + lr) * LDSK + g8];
        #pragma unroll
        for (int m = 0; m < 4; ++m)
            #pragma unroll
            for (int n = 0; n < 4; ++n)
                acc[m][n] = __builtin_amdgcn_mfma_f32_16x16x32_bf16(af[m], bfr[n], acc[m][n], 0, 0, 0);
        __syncthreads();
    }

    // C/D layout: col = lane&15, row = (lane>>4)*4 + i   [measured: learn_hip m89]
    #pragma unroll
    for (int m = 0; m < 4; ++m) {
        int row0 = mBase + wm + m * 16 + (lane >> 4) * 4;
        #pragma unroll
        for (int n = 0; n < 4; ++n) {
            int col = nBase + wn + n * 16 + lr;
            #pragma unroll
            for (int i = 0; i < 4; ++i) {
                int row = row0 + i;
                if (row < KKEEP)
                    Cb[(size_t)row * DDIM + col] = acc[m][n][i];
            }
        }
    }
}

extern "C" void kernel_launch(void* const* d_in, const int* in_sizes, int n_in,
                              void* d_out, int out_size, void* d_ws, size_t ws_size,
                              hipStream_t stream)
{
    const float* x = (const float*)d_in[0];
    float* out  = (float*)d_out;
    float* xrec = out;                                      // [64*922*768]
    float* xdct = out + (size_t)NBATCH * KKEEP * DDIM;      // [64*922*768]

    __hip_bfloat16* C1 = (__hip_bfloat16*)d_ws;                       // [1024][1024] bf16
    __hip_bfloat16* A2 = (__hip_bfloat16*)d_ws + 1024 * 1024;         // [1024][928]  bf16

    gen_C1<<<(1024 * 1024 + 255) / 256, 256, 0, stream>>>(C1);
    gen_C2T<<<(1024 * 928 + 255) / 256, 256, 0, stream>>>(A2);

    dim3 grid(DDIM / BN, 1024 / BM, NBATCH);   // (6, 8, 64)

    // Stage 1: x_dct = C_T[:922] @ x[b]   (K = 1024, 32 steps)
    gemm_dct<<<grid, 256, 0, stream>>>(C1, 1024, 32,
                                       x, T_LEN, (long long)T_LEN * DDIM,
                                       xdct, (long long)KKEEP * DDIM);

    // Stage 2: x_rec = C_k^T @ x_dct[b]   (K = 922 -> 29 padded steps of 32)
    gemm_dct<<<grid, 256, 0, stream>>>(A2, 928, 29,
                                       xdct, KKEEP, (long long)KKEEP * DDIM,
                                       xrec, (long long)KKEEP * DDIM);
}

// Round 3
// 790.965 us; speedup vs baseline: 1.2349x; 1.2349x over previous
//
#include <hip/hip_runtime.h>
#include <hip/hip_bf16.h>

typedef __attribute__((ext_vector_type(8))) short short8;
typedef __attribute__((ext_vector_type(4))) float f32x4;

#define T_LEN   1024
#define KKEEP   922
#define DDIM    768
#define NBATCH  64

// ---------------- DCT matrix generators (bf16, in d_ws) ----------------

// C1[k][t] = DCT-II(ortho, N=1024), rows >= 922 zeroed. [1024][1024]
__global__ void gen_C1(__hip_bfloat16* __restrict__ C1) {
    int idx = blockIdx.x * 256 + threadIdx.x;
    if (idx >= 1024 * 1024) return;
    int kk = idx >> 10;
    int t  = idx & 1023;
    float val = 0.0f;
    if (kk < KKEEP) {
        float a1 = 3.14159265358979323846f * (2.0f * (float)t + 1.0f);
        float a2 = a1 * (float)kk;
        float a3 = a2 / 2048.0f;
        float s  = (kk == 0) ? sqrtf(1.0f / 1024.0f) : sqrtf(2.0f / 1024.0f);
        val = s * cosf(a3);
    }
    C1[idx] = __float2bfloat16(val);
}

// A2[n][m] = C_k[m][n] (ortho DCT-III = transpose of DCT-II size 922),
// [1024][928], zero-padded both dims.
__global__ void gen_C2T(__hip_bfloat16* __restrict__ A2) {
    int idx = blockIdx.x * 256 + threadIdx.x;
    if (idx >= 1024 * 928) return;
    int n = idx / 928;
    int m = idx - n * 928;
    float val = 0.0f;
    if (n < KKEEP && m < KKEEP) {
        float a1 = 3.14159265358979323846f * (2.0f * (float)n + 1.0f);
        float a2 = a1 * (float)m;
        float a3 = a2 / 1844.0f;
        float s  = (m == 0) ? sqrtf(1.0f / 922.0f) : sqrtf(2.0f / 922.0f);
        val = s * cosf(a3);
    }
    A2[idx] = __float2bfloat16(val);
}

// ---------------- transpose + fp32->bf16 convert ----------------
// in:  [Z][R][C] fp32 (C % 64 == 0); out: [Z][C][Rp] bf16 (Rp % 16 == 0,
// Rp >= R, cols R..Rp zero). 64x64 tile per block, 256 threads.
__global__ __launch_bounds__(256)
void transpose_cvt(const float* __restrict__ in, __hip_bfloat16* __restrict__ out,
                   int R, int C, int Rp)
{
    __shared__ float tile[64][65];
    const int r0 = blockIdx.x * 64, c0 = blockIdx.y * 64, z = blockIdx.z;
    const float* inz = in + (size_t)z * R * C;
    __hip_bfloat16* outz = out + (size_t)z * C * Rp;
    const int tid = threadIdx.x;
    const int lr = tid >> 4, lc4 = (tid & 15) * 4;
    #pragma unroll
    for (int i = 0; i < 4; ++i) {
        int row = i * 16 + lr;
        int gr  = r0 + row;
        float4 v = make_float4(0.f, 0.f, 0.f, 0.f);
        if (gr < R) v = *(const float4*)(inz + (size_t)gr * C + c0 + lc4);
        tile[row][lc4 + 0] = v.x; tile[row][lc4 + 1] = v.y;
        tile[row][lc4 + 2] = v.z; tile[row][lc4 + 3] = v.w;
    }
    __syncthreads();
    const int orow = tid >> 2, seg = tid & 3;
    const int rB = r0 + seg * 16;
    if (rB < Rp) {
        alignas(16) __hip_bfloat16 tmp[16];
        #pragma unroll
        for (int j = 0; j < 16; ++j)
            tmp[j] = __float2bfloat16(tile[seg * 16 + j][orow]);
        uint4* dst = (uint4*)(outz + (size_t)(c0 + orow) * Rp + rB);
        dst[0] = ((const uint4*)tmp)[0];
        dst[1] = ((const uint4*)tmp)[1];
    }
}

// ---------------- m97-style bf16 GEMM ----------------
// C[z][m][n] (fp32, rows < KKEEP written) = A[m][:] . B[z][n][:]
// A: [>=128*gridDim.y][lda] bf16 row-major (K contiguous)
// B: [z][768][ldb] bf16 row-major (K contiguous)
// 128x128 tile, BK=32, global_load_lds width 16, linear LDS, dbuf, 4 waves.
__global__ __launch_bounds__(256)
void gemm_bf16(const __hip_bfloat16* __restrict__ A, int lda,
               const __hip_bfloat16* __restrict__ B, int ldb, long long bStride,
               float* __restrict__ C, long long cStride, int ksteps)
{
    __shared__ __hip_bfloat16 As[2][128 * 32];
    __shared__ __hip_bfloat16 Bs[2][128 * 32];

    const int tid   = threadIdx.x;
    const int mBase = blockIdx.y * 128;
    const int nBase = blockIdx.x * 128;
    const __hip_bfloat16* __restrict__ Bb = B + (long long)blockIdx.z * bStride;
    float* __restrict__ Cb = C + (long long)blockIdx.z * cStride;

    // 512 16B-chunks per 128x32 tile; thread t stages chunks t and t+256.
    // LDS dest = chunk*16 bytes (wave-uniform base + lane*16 within each wave).
    auto stage = [&](int buf, int k0) {
        #pragma unroll
        for (int h = 0; h < 2; ++h) {
            int c = h * 256 + tid;
            int row = c >> 2, q = c & 3;
            const __hip_bfloat16* ga = A + (size_t)(mBase + row) * lda + k0 + q * 8;
            __builtin_amdgcn_global_load_lds(
                (const __attribute__((address_space(1))) void*)ga,
                (__attribute__((address_space(3))) void*)(&As[buf][c * 8]), 16, 0, 0);
            const __hip_bfloat16* gb = Bb + (size_t)(nBase + row) * ldb + k0 + q * 8;
            __builtin_amdgcn_global_load_lds(
                (const __attribute__((address_space(1))) void*)gb,
                (__attribute__((address_space(3))) void*)(&Bs[buf][c * 8]), 16, 0, 0);
        }
    };

    const int lane = tid & 63;
    const int wid  = tid >> 6;
    const int wm   = (wid >> 1) * 64;
    const int wn   = (wid & 1) * 64;
    const int lr   = lane & 15;
    const int g8   = (lane >> 4) * 8;

    f32x4 acc[4][4] = {};

    stage(0, 0);
    for (int s = 0; s < ksteps; ++s) {
        int buf = s & 1;
        __syncthreads();                       // drains vmcnt -> buf ready
        if (s + 1 < ksteps) stage(buf ^ 1, (s + 1) * 32);   // async, fire-and-forget
        short8 af[4], bfr[4];
        #pragma unroll
        for (int m = 0; m < 4; ++m)
            af[m] = *(const short8*)&As[buf][(wm + m * 16 + lr) * 32 + g8];
        #pragma unroll
        for (int n = 0; n < 4; ++n)
            bfr[n] = *(const short8*)&Bs[buf][(wn + n * 16 + lr) * 32 + g8];
        #pragma unroll
        for (int m = 0; m < 4; ++m)
            #pragma unroll
            for (int n = 0; n < 4; ++n)
                acc[m][n] = __builtin_amdgcn_mfma_f32_16x16x32_bf16(af[m], bfr[n], acc[m][n], 0, 0, 0);
    }

    // C/D layout: col = lane&15, row = (lane>>4)*4 + i   [measured: learn_hip m89]
    #pragma unroll
    for (int m = 0; m < 4; ++m) {
        int row0 = mBase + wm + m * 16 + (lane >> 4) * 4;
        #pragma unroll
        for (int n = 0; n < 4; ++n) {
            int col = nBase + wn + n * 16 + lr;
            #pragma unroll
            for (int i = 0; i < 4; ++i) {
                int row = row0 + i;
                if (row < KKEEP)
                    Cb[(size_t)row * DDIM + col] = acc[m][n][i];
            }
        }
    }
}

// ---------------- fallback stage-2 GEMM (fp32 B, proven in Round 2) ----------------
#define BK 32
#define LDSK 40
__global__ __launch_bounds__(256)
void gemm_dct(const __hip_bfloat16* __restrict__ A, int lda, int ksteps,
              const float* __restrict__ B, int bRows, long long bStride,
              float* __restrict__ C, long long cStride)
{
    __shared__ __hip_bfloat16 As[2][128 * LDSK];
    __shared__ __hip_bfloat16 Bs[2][128 * LDSK];
    const int tid   = threadIdx.x;
    const int mBase = blockIdx.y * 128;
    const int nBase = blockIdx.x * 128;
    const float* __restrict__ Bb = B + (long long)blockIdx.z * bStride;
    float* __restrict__       Cb = C + (long long)blockIdx.z * cStride;

    auto stageA = [&](int buf, int k0) {
        int r = tid >> 1, half = tid & 1;
        const uint4* src = (const uint4*)(A + (size_t)(mBase + r) * lda + k0 + half * 16);
        uint4 v0 = src[0], v1 = src[1];
        uint4* dst = (uint4*)&As[buf][r * LDSK + half * 16];
        dst[0] = v0; dst[1] = v1;
    };
    auto stageB = [&](int buf, int k0) {
        #pragma unroll
        for (int p = 0; p < 4; ++p) {
            int idx = p * 256 + tid;
            int k   = idx & 31;
            int n4  = (idx >> 5) * 4;
            int gk  = k0 + k;
            float4 v = make_float4(0.f, 0.f, 0.f, 0.f);
            if (gk < bRows) v = *(const float4*)(Bb + (size_t)gk * DDIM + nBase + n4);
            __hip_bfloat16* d = &Bs[buf][n4 * LDSK + k];
            d[0 * LDSK] = __float2bfloat16(v.x);
            d[1 * LDSK] = __float2bfloat16(v.y);
            d[2 * LDSK] = __float2bfloat16(v.z);
            d[3 * LDSK] = __float2bfloat16(v.w);
        }
    };

    const int lane = tid & 63;
    const int wid  = tid >> 6;
    const int wm   = (wid >> 1) * 64;
    const int wn   = (wid & 1) * 64;
    const int lr   = lane & 15;
    const int g8   = (lane >> 4) * 8;
    f32x4 acc[4][4] = {};

    stageA(0, 0);
    stageB(0, 0);
    __syncthreads();
    for (int s = 0; s < ksteps; ++s) {
        int buf = s & 1;
        if (s + 1 < ksteps) {
            stageA(buf ^ 1, (s + 1) * BK);
            stageB(buf ^ 1, (s + 1) * BK);
        }
        short8 af[4], bfr[4];
        #pragma unroll
        for (int m = 0; m < 4; ++m)
            af[m] = *(const short8*)&As[buf][(wm + m * 16 + lr) * LDSK + g8];
        #pragma unroll
        for (int n = 0; n < 4; ++n)
            bfr[n] = *(const short8*)&Bs[buf][(wn + n * 16 + lr) * LDSK + g8];
        #pragma unroll
        for (int m = 0; m < 4; ++m)
            #pragma unroll
            for (int n = 0; n < 4; ++n)
                acc[m][n] = __builtin_amdgcn_mfma_f32_16x16x32_bf16(af[m], bfr[n], acc[m][n], 0, 0, 0);
        __syncthreads();
    }
    #pragma unroll
    for (int m = 0; m < 4; ++m) {
        int row0 = mBase + wm + m * 16 + (lane >> 4) * 4;
        #pragma unroll
        for (int n = 0; n < 4; ++n) {
            int col = nBase + wn + n * 16 + lr;
            #pragma unroll
            for (int i = 0; i < 4; ++i) {
                int row = row0 + i;
                if (row < KKEEP)
                    Cb[(size_t)row * DDIM + col] = acc[m][n][i];
            }
        }
    }
}

// ---------------- host ----------------
extern "C" void kernel_launch(void* const* d_in, const int* in_sizes, int n_in,
                              void* d_out, int out_size, void* d_ws, size_t ws_size,
                              hipStream_t stream)
{
    const float* x = (const float*)d_in[0];
    float* out  = (float*)d_out;
    float* xrec = out;                                      // [64*922*768] fp32
    float* xdct = out + (size_t)NBATCH * KKEEP * DDIM;      // [64*922*768] fp32

    const size_t SZ_C1  = 1024ull * 1024;        // bf16 elements
    const size_t SZ_A2  = 1024ull * 928;
    const size_t SZ_XDT = 64ull * 768 * 928;     // xdct^T bf16

    __hip_bfloat16* C1 = (__hip_bfloat16*)d_ws;
    __hip_bfloat16* A2 = C1 + SZ_C1;
    const bool bigws = ws_size >= (SZ_C1 + SZ_A2 + SZ_XDT) * 2;
    __hip_bfloat16* xdT = A2 + SZ_A2;            // only used if bigws

    // x^T bf16 [64][768][1024] lives in the xrec region (dead until GEMM2).
    __hip_bfloat16* xT = (__hip_bfloat16*)xrec;

    gen_C1<<<(1024 * 1024 + 255) / 256, 256, 0, stream>>>(C1);
    gen_C2T<<<(1024 * 928 + 255) / 256, 256, 0, stream>>>(A2);

    // x [z][1024][768] f32 -> xT [z][768][1024] bf16
    transpose_cvt<<<dim3(16, 12, NBATCH), 256, 0, stream>>>(x, xT, 1024, DDIM, 1024);

    dim3 grid(DDIM / 128, 1024 / 128, NBATCH);   // (6, 8, 64)

    // Stage 1: x_dct[m][d] = sum_t C1[m][t] * xT[d][t]   (K=1024, 32 steps)
    gemm_bf16<<<grid, 256, 0, stream>>>(C1, 1024, xT, 1024,
                                        (long long)DDIM * 1024,
                                        xdct, (long long)KKEEP * DDIM, 32);

    if (bigws) {
        // xdct [z][922][768] f32 -> xdT [z][768][928] bf16
        transpose_cvt<<<dim3(15, 12, NBATCH), 256, 0, stream>>>(xdct, xdT, KKEEP, DDIM, 928);
        // Stage 2: x_rec[n][d] = sum_m A2[n][m] * xdT[d][m]  (K=928, 29 steps)
        gemm_bf16<<<grid, 256, 0, stream>>>(A2, 928, xdT, 928,
                                            (long long)DDIM * 928,
                                            xrec, (long long)KKEEP * DDIM, 29);
    } else {
        // ws too small for xdct^T: proven fp32-B path for stage 2.
        gemm_dct<<<grid, 256, 0, stream>>>(A2, 928, 29,
                                           xdct, KKEEP, (long long)KKEEP * DDIM,
                                           xrec, (long long)KKEEP * DDIM);
    }
}

// Round 5
// 782.229 us; speedup vs baseline: 1.2487x; 1.0112x over previous
//
#include <hip/hip_runtime.h>
#include <hip/hip_bf16.h>

typedef __attribute__((ext_vector_type(8))) short short8;
typedef __attribute__((ext_vector_type(4))) float f32x4;

#define T_LEN   1024
#define KKEEP   922
#define DDIM    768
#define NBATCH  64

// ---------------- DCT matrix generators (bf16, in d_ws) ----------------

// C1[k][t] = DCT-II(ortho, N=1024), rows >= 922 zeroed. [1024][1024]
__global__ void gen_C1(__hip_bfloat16* __restrict__ C1) {
    int idx = blockIdx.x * 256 + threadIdx.x;
    if (idx >= 1024 * 1024) return;
    int kk = idx >> 10;
    int t  = idx & 1023;
    float val = 0.0f;
    if (kk < KKEEP) {
        float a1 = 3.14159265358979323846f * (2.0f * (float)t + 1.0f);
        float a2 = a1 * (float)kk;
        float a3 = a2 / 2048.0f;
        float s  = (kk == 0) ? sqrtf(1.0f / 1024.0f) : sqrtf(2.0f / 1024.0f);
        val = s * cosf(a3);
    }
    C1[idx] = __float2bfloat16(val);
}

// A2[n][m] = C_k[m][n] (ortho DCT-III = transpose of DCT-II size 922),
// [1024][928], zero-padded both dims.
__global__ void gen_C2T(__hip_bfloat16* __restrict__ A2) {
    int idx = blockIdx.x * 256 + threadIdx.x;
    if (idx >= 1024 * 928) return;
    int n = idx / 928;
    int m = idx - n * 928;
    float val = 0.0f;
    if (n < KKEEP && m < KKEEP) {
        float a1 = 3.14159265358979323846f * (2.0f * (float)n + 1.0f);
        float a2 = a1 * (float)m;
        float a3 = a2 / 1844.0f;
        float s  = (m == 0) ? sqrtf(1.0f / 922.0f) : sqrtf(2.0f / 922.0f);
        val = s * cosf(a3);
    }
    A2[idx] = __float2bfloat16(val);
}

// ---------------- transpose + fp32->bf16 convert (x only) ----------------
// in: [Z][R][C] fp32 (C % 64 == 0); out: [Z][C][Rp] bf16.
__global__ __launch_bounds__(256)
void transpose_cvt(const float* __restrict__ in, __hip_bfloat16* __restrict__ out,
                   int R, int C, int Rp)
{
    __shared__ float tile[64][65];
    const int r0 = blockIdx.x * 64, c0 = blockIdx.y * 64, z = blockIdx.z;
    const float* inz = in + (size_t)z * R * C;
    __hip_bfloat16* outz = out + (size_t)z * C * Rp;
    const int tid = threadIdx.x;
    const int lr = tid >> 4, lc4 = (tid & 15) * 4;
    #pragma unroll
    for (int i = 0; i < 4; ++i) {
        int row = i * 16 + lr;
        int gr  = r0 + row;
        float4 v = make_float4(0.f, 0.f, 0.f, 0.f);
        if (gr < R) v = *(const float4*)(inz + (size_t)gr * C + c0 + lc4);
        tile[row][lc4 + 0] = v.x; tile[row][lc4 + 1] = v.y;
        tile[row][lc4 + 2] = v.z; tile[row][lc4 + 3] = v.w;
    }
    __syncthreads();
    const int orow = tid >> 2, seg = tid & 3;
    const int rB = r0 + seg * 16;
    if (rB < Rp) {
        alignas(16) __hip_bfloat16 tmp[16];
        #pragma unroll
        for (int j = 0; j < 16; ++j)
            tmp[j] = __float2bfloat16(tile[seg * 16 + j][orow]);
        uint4* dst = (uint4*)(outz + (size_t)(c0 + orow) * Rp + rB);
        dst[0] = ((const uint4*)tmp)[0];
        dst[1] = ((const uint4*)tmp)[1];
    }
}

// ---------------- m97-style bf16 GEMM, XCD-swizzled, optional fused T-write ----
// Fixed grid (6, 8, 64). C[z][m][n] fp32 (m < KKEEP); if WRT, also writes
// DT[z][n][m] bf16 (m < 928) — the transposed bf16 copy for the next GEMM.
template <bool WRT>
__global__ __launch_bounds__(256)
void gemm_bf16(const __hip_bfloat16* __restrict__ A, int lda,
               const __hip_bfloat16* __restrict__ B, int ldb, long long bStride,
               float* __restrict__ C, long long cStride, int ksteps,
               __hip_bfloat16* __restrict__ DT, int ldt, long long dtStride)
{
    __shared__ __hip_bfloat16 As[2][128 * 32];
    __shared__ __hip_bfloat16 Bs[2][128 * 32];

    // T1: bijective XCD chunk swizzle. nwg = 3072, 384 contiguous work items
    // per XCD -> 8 full z-slabs each; the 8 y-blocks sharing a B-panel stay
    // on one XCD's L2.
    const int orig = blockIdx.x + 6 * (blockIdx.y + 8 * blockIdx.z);
    const int w    = (orig & 7) * 384 + (orig >> 3);
    const int bx   = w % 6;
    const int tmp  = w / 6;
    const int by   = tmp & 7;
    const int bz   = tmp >> 3;

    const int tid   = threadIdx.x;
    const int mBase = by * 128;
    const int nBase = bx * 128;
    const __hip_bfloat16* __restrict__ Bb = B + (long long)bz * bStride;
    float* __restrict__ Cb = C + (long long)bz * cStride;
    __hip_bfloat16* __restrict__ DTb = WRT ? (DT + (long long)bz * dtStride) : nullptr;

    auto stage = [&](int buf, int k0) {
        #pragma unroll
        for (int h = 0; h < 2; ++h) {
            int c = h * 256 + tid;
            int row = c >> 2, q = c & 3;
            const __hip_bfloat16* ga = A + (size_t)(mBase + row) * lda + k0 + q * 8;
            __builtin_amdgcn_global_load_lds(
                (const __attribute__((address_space(1))) void*)ga,
                (__attribute__((address_space(3))) void*)(&As[buf][c * 8]), 16, 0, 0);
            const __hip_bfloat16* gb = Bb + (size_t)(nBase + row) * ldb + k0 + q * 8;
            __builtin_amdgcn_global_load_lds(
                (const __attribute__((address_space(1))) void*)gb,
                (__attribute__((address_space(3))) void*)(&Bs[buf][c * 8]), 16, 0, 0);
        }
    };

    const int lane = tid & 63;
    const int wid  = tid >> 6;
    const int wm   = (wid >> 1) * 64;
    const int wn   = (wid & 1) * 64;
    const int lr   = lane & 15;
    const int g8   = (lane >> 4) * 8;

    f32x4 acc[4][4] = {};

    stage(0, 0);
    for (int s = 0; s < ksteps; ++s) {
        int buf = s & 1;
        __syncthreads();                        // drains vmcnt -> buf ready
        if (s + 1 < ksteps) stage(buf ^ 1, (s + 1) * 32);
        short8 af[4], bfr[4];
        #pragma unroll
        for (int m = 0; m < 4; ++m)
            af[m] = *(const short8*)&As[buf][(wm + m * 16 + lr) * 32 + g8];
        #pragma unroll
        for (int n = 0; n < 4; ++n)
            bfr[n] = *(const short8*)&Bs[buf][(wn + n * 16 + lr) * 32 + g8];
        #pragma unroll
        for (int m = 0; m < 4; ++m)
            #pragma unroll
            for (int n = 0; n < 4; ++n)
                acc[m][n] = __builtin_amdgcn_mfma_f32_16x16x32_bf16(af[m], bfr[n], acc[m][n], 0, 0, 0);
    }

    // C/D layout: col = lane&15, row = (lane>>4)*4 + i   [measured: learn_hip m89]
    #pragma unroll
    for (int m = 0; m < 4; ++m) {
        int row0 = mBase + wm + m * 16 + (lane >> 4) * 4;
        #pragma unroll
        for (int n = 0; n < 4; ++n) {
            int col = nBase + wn + n * 16 + lr;
            #pragma unroll
            for (int i = 0; i < 4; ++i) {
                int row = row0 + i;
                if (row < KKEEP)
                    Cb[(size_t)row * DDIM + col] = acc[m][n][i];
            }
            if (WRT && row0 < 928) {   // row0 % 4 == 0, so all 4 rows < 928
                union { ushort4 u; __hip_bfloat16 h[4]; } t;
                #pragma unroll
                for (int i = 0; i < 4; ++i) t.h[i] = __float2bfloat16(acc[m][n][i]);
                *(ushort4*)(DTb + (size_t)col * ldt + row0) = t.u;
            }
        }
    }
}

// ---------------- fallback stage-2 GEMM (fp32 B) — only if ws too small ------
#define BK 32
#define LDSK 40
__global__ __launch_bounds__(256)
void gemm_dct(const __hip_bfloat16* __restrict__ A, int lda, int ksteps,
              const float* __restrict__ B, int bRows, long long bStride,
              float* __restrict__ C, long long cStride)
{
    __shared__ __hip_bfloat16 As[2][128 * LDSK];
    __shared__ __hip_bfloat16 Bs[2][128 * LDSK];
    const int tid   = threadIdx.x;
    const int mBase = blockIdx.y * 128;
    const int nBase = blockIdx.x * 128;
    const float* __restrict__ Bb = B + (long long)blockIdx.z * bStride;
    float* __restrict__       Cb = C + (long long)blockIdx.z * cStride;

    auto stageA = [&](int buf, int k0) {
        int r = tid >> 1, half = tid & 1;
        const uint4* src = (const uint4*)(A + (size_t)(mBase + r) * lda + k0 + half * 16);
        uint4 v0 = src[0], v1 = src[1];
        uint4* dst = (uint4*)&As[buf][r * LDSK + half * 16];
        dst[0] = v0; dst[1] = v1;
    };
    auto stageB = [&](int buf, int k0) {
        #pragma unroll
        for (int p = 0; p < 4; ++p) {
            int idx = p * 256 + tid;
            int k   = idx & 31;
            int n4  = (idx >> 5) * 4;
            int gk  = k0 + k;
            float4 v = make_float4(0.f, 0.f, 0.f, 0.f);
            if (gk < bRows) v = *(const float4*)(Bb + (size_t)gk * DDIM + nBase + n4);
            __hip_bfloat16* d = &Bs[buf][n4 * LDSK + k];
            d[0 * LDSK] = __float2bfloat16(v.x);
            d[1 * LDSK] = __float2bfloat16(v.y);
            d[2 * LDSK] = __float2bfloat16(v.z);
            d[3 * LDSK] = __float2bfloat16(v.w);
        }
    };

    const int lane = tid & 63;
    const int wid  = tid >> 6;
    const int wm   = (wid >> 1) * 64;
    const int wn   = (wid & 1) * 64;
    const int lr   = lane & 15;
    const int g8   = (lane >> 4) * 8;
    f32x4 acc[4][4] = {};

    stageA(0, 0);
    stageB(0, 0);
    __syncthreads();
    for (int s = 0; s < ksteps; ++s) {
        int buf = s & 1;
        if (s + 1 < ksteps) {
            stageA(buf ^ 1, (s + 1) * BK);
            stageB(buf ^ 1, (s + 1) * BK);
        }
        short8 af[4], bfr[4];
        #pragma unroll
        for (int m = 0; m < 4; ++m)
            af[m] = *(const short8*)&As[buf][(wm + m * 16 + lr) * LDSK + g8];
        #pragma unroll
        for (int n = 0; n < 4; ++n)
            bfr[n] = *(const short8*)&Bs[buf][(wn + n * 16 + lr) * LDSK + g8];
        #pragma unroll
        for (int m = 0; m < 4; ++m)
            #pragma unroll
            for (int n = 0; n < 4; ++n)
                acc[m][n] = __builtin_amdgcn_mfma_f32_16x16x32_bf16(af[m], bfr[n], acc[m][n], 0, 0, 0);
        __syncthreads();
    }
    #pragma unroll
    for (int m = 0; m < 4; ++m) {
        int row0 = mBase + wm + m * 16 + (lane >> 4) * 4;
        #pragma unroll
        for (int n = 0; n < 4; ++n) {
            int col = nBase + wn + n * 16 + lr;
            #pragma unroll
            for (int i = 0; i < 4; ++i) {
                int row = row0 + i;
                if (row < KKEEP)
                    Cb[(size_t)row * DDIM + col] = acc[m][n][i];
            }
        }
    }
}

// ---------------- host ----------------
extern "C" void kernel_launch(void* const* d_in, const int* in_sizes, int n_in,
                              void* d_out, int out_size, void* d_ws, size_t ws_size,
                              hipStream_t stream)
{
    const float* x = (const float*)d_in[0];
    float* out  = (float*)d_out;
    float* xrec = out;                                      // [64*922*768] fp32
    float* xdct = out + (size_t)NBATCH * KKEEP * DDIM;      // [64*922*768] fp32

    const size_t SZ_C1  = 1024ull * 1024;        // bf16 elements
    const size_t SZ_A2  = 1024ull * 928;
    const size_t SZ_XDT = 64ull * 768 * 928;     // xdct^T bf16

    __hip_bfloat16* C1 = (__hip_bfloat16*)d_ws;
    __hip_bfloat16* A2 = C1 + SZ_C1;
    const bool bigws = ws_size >= (SZ_C1 + SZ_A2 + SZ_XDT) * 2;
    __hip_bfloat16* xdT = A2 + SZ_A2;            // only used if bigws

    // x^T bf16 [64][768][1024] lives in the xrec region (dead until GEMM2).
    __hip_bfloat16* xT = (__hip_bfloat16*)xrec;

    gen_C1<<<(1024 * 1024 + 255) / 256, 256, 0, stream>>>(C1);
    gen_C2T<<<(1024 * 928 + 255) / 256, 256, 0, stream>>>(A2);

    // x [z][1024][768] f32 -> xT [z][768][1024] bf16
    transpose_cvt<<<dim3(16, 12, NBATCH), 256, 0, stream>>>(x, xT, 1024, DDIM, 1024);

    dim3 grid(DDIM / 128, 1024 / 128, NBATCH);   // (6, 8, 64) — gemm_bf16 assumes this

    if (bigws) {
        // Stage 1: x_dct = C1 @ x^T; fused epilogue also emits xdT bf16.
        gemm_bf16<true><<<grid, 256, 0, stream>>>(C1, 1024, xT, 1024,
                                                  (long long)DDIM * 1024,
                                                  xdct, (long long)KKEEP * DDIM, 32,
                                                  xdT, 928, (long long)DDIM * 928);
        // Stage 2: x_rec = A2 @ xdT   (K = 928, 29 steps)
        gemm_bf16<false><<<grid, 256, 0, stream>>>(A2, 928, xdT, 928,
                                                   (long long)DDIM * 928,
                                                   xrec, (long long)KKEEP * DDIM, 29,
                                                   nullptr, 0, 0);
    } else {
        gemm_bf16<false><<<grid, 256, 0, stream>>>(C1, 1024, xT, 1024,
                                                   (long long)DDIM * 1024,
                                                   xdct, (long long)KKEEP * DDIM, 32,
                                                   nullptr, 0, 0);
        gemm_dct<<<grid, 256, 0, stream>>>(A2, 928, 29,
                                           xdct, KKEEP, (long long)KKEEP * DDIM,
                                           xrec, (long long)KKEEP * DDIM);
    }
}